// Round 1
// baseline (469.021 us; speedup 1.0000x reference)
//
#include <hip/hip_runtime.h>
#include <hip/hip_bf16.h>
#include <stdint.h>

#define NN 50000
#define NE 1600000

__device__ __forceinline__ float bf_lo(uint32_t v){ return __uint_as_float(v << 16); }
__device__ __forceinline__ float bf_hi(uint32_t v){ return __uint_as_float(v & 0xffff0000u); }
__device__ __forceinline__ unsigned short f2bf(float f){
  uint32_t u = __float_as_uint(f);
  uint32_t r = (u + 0x7fffu + ((u >> 16) & 1u)) >> 16;   // RNE
  return (unsigned short)r;
}

// ---------------- graph preprocessing ----------------
__global__ void k_count(const int* __restrict__ dst, int* __restrict__ deg){
  int i = blockIdx.x * 256 + threadIdx.x;
  if (i < NE) atomicAdd(&deg[dst[i]], 1);
}

__global__ void k_dinv(const int* __restrict__ deg, float* __restrict__ dinv){
  int i = blockIdx.x * 256 + threadIdx.x;
  if (i < NN) dinv[i] = rsqrtf((float)(deg[i] + 1));   // +1 self-loop; deg>=1 always
}

__global__ void k_scan1(const int* __restrict__ deg, int* __restrict__ offs, int* __restrict__ bsum){
  __shared__ int lds[1024];
  int i = blockIdx.x * 1024 + threadIdx.x;
  int v = (i < NN) ? deg[i] : 0;
  lds[threadIdx.x] = v;
  __syncthreads();
  for (int ofs = 1; ofs < 1024; ofs <<= 1){
    int t = (threadIdx.x >= ofs) ? lds[threadIdx.x - ofs] : 0;
    __syncthreads();
    lds[threadIdx.x] += t;
    __syncthreads();
  }
  if (i < NN) offs[i] = lds[threadIdx.x] - v;           // exclusive
  if (threadIdx.x == 1023) bsum[blockIdx.x] = lds[1023];
}

__global__ void k_scan2(int* __restrict__ bsum, int* __restrict__ offs, int nb){
  if (blockIdx.x == 0 && threadIdx.x == 0){
    int run = 0;
    for (int b = 0; b < nb; ++b){ int t = bsum[b]; bsum[b] = run; run += t; }
    offs[NN] = run;                                     // == NE
  }
}

__global__ void k_scan3(int* __restrict__ offs, const int* __restrict__ bsum){
  int i = blockIdx.x * 1024 + threadIdx.x;
  if (i < NN) offs[i] += bsum[blockIdx.x];
}

__global__ void k_fill(const int* __restrict__ src, const int* __restrict__ dst,
                       const int* __restrict__ offs, int* __restrict__ ctr, int* __restrict__ csr){
  int e = blockIdx.x * 256 + threadIdx.x;
  if (e < NE){
    int d = dst[e];
    int p = atomicAdd(&ctr[d], 1);
    csr[offs[d] + p] = src[e];
  }
}

// ---------------- GEMM 1: h1s = (seq @ W1) * dinv[row], bf16 out ----------------
// A [NN,256] fp32, B [256,128] fp32, H [NN,128] bf16. 32 rows x 128 cols per block.
__global__ __launch_bounds__(256) void k_gemm1(const float* __restrict__ A, const float* __restrict__ B,
                                               const float* __restrict__ dinv, unsigned short* __restrict__ H){
  const int tid = threadIdx.x;
  const int cx = (tid & 31) * 4;          // 0..124
  const int ry = (tid >> 5) * 4;          // 0..28
  const int rbase = blockIdx.x * 32 + ry;
  float acc[4][4] = {};
  for (int k = 0; k < 256; k += 4){
    float4 b[4];
    #pragma unroll
    for (int kk = 0; kk < 4; ++kk) b[kk] = *(const float4*)&B[(k + kk) * 128 + cx];
    #pragma unroll
    for (int i = 0; i < 4; ++i){
      int r = rbase + i; if (r >= NN) r = NN - 1;
      float4 a = *(const float4*)&A[(size_t)r * 256 + k];
      acc[i][0] += a.x*b[0].x + a.y*b[1].x + a.z*b[2].x + a.w*b[3].x;
      acc[i][1] += a.x*b[0].y + a.y*b[1].y + a.z*b[2].y + a.w*b[3].y;
      acc[i][2] += a.x*b[0].z + a.y*b[1].z + a.z*b[2].z + a.w*b[3].z;
      acc[i][3] += a.x*b[0].w + a.y*b[1].w + a.z*b[2].w + a.w*b[3].w;
    }
  }
  #pragma unroll
  for (int i = 0; i < 4; ++i){
    int r = rbase + i;
    if (r < NN){
      float s = dinv[r];
      ushort4 w;
      w.x = f2bf(acc[i][0] * s); w.y = f2bf(acc[i][1] * s);
      w.z = f2bf(acc[i][2] * s); w.w = f2bf(acc[i][3] * s);
      *(ushort4*)&H[(size_t)r * 128 + cx] = w;
    }
  }
}

// ---------------- GEMM 2: h2s = (res1 @ W2) * dinv[row], bf16 out ----------------
// A [NN,128] fp32, B [128,64] fp32, H [NN,64] bf16. 32 rows x 64 cols per block.
__global__ __launch_bounds__(256) void k_gemm2(const float* __restrict__ A, const float* __restrict__ B,
                                               const float* __restrict__ dinv, unsigned short* __restrict__ H){
  const int tid = threadIdx.x;
  const int cx = (tid & 15) * 4;          // 0..60
  const int ry = (tid >> 4) * 2;          // 0..30
  const int rbase = blockIdx.x * 32 + ry;
  float acc[2][4] = {};
  for (int k = 0; k < 128; k += 4){
    float4 b[4];
    #pragma unroll
    for (int kk = 0; kk < 4; ++kk) b[kk] = *(const float4*)&B[(k + kk) * 64 + cx];
    #pragma unroll
    for (int i = 0; i < 2; ++i){
      int r = rbase + i; if (r >= NN) r = NN - 1;
      float4 a = *(const float4*)&A[(size_t)r * 128 + k];
      acc[i][0] += a.x*b[0].x + a.y*b[1].x + a.z*b[2].x + a.w*b[3].x;
      acc[i][1] += a.x*b[0].y + a.y*b[1].y + a.z*b[2].y + a.w*b[3].y;
      acc[i][2] += a.x*b[0].z + a.y*b[1].z + a.z*b[2].z + a.w*b[3].z;
      acc[i][3] += a.x*b[0].w + a.y*b[1].w + a.z*b[2].w + a.w*b[3].w;
    }
  }
  #pragma unroll
  for (int i = 0; i < 2; ++i){
    int r = rbase + i;
    if (r < NN){
      float s = dinv[r];
      ushort4 w;
      w.x = f2bf(acc[i][0] * s); w.y = f2bf(acc[i][1] * s);
      w.z = f2bf(acc[i][2] * s); w.w = f2bf(acc[i][3] * s);
      *(ushort4*)&H[(size_t)r * 64 + cx] = w;
    }
  }
}

// ---------------- aggregation 1: res1 = dinv*(h1s[self] + sum h1s[src]) + b1 ----------------
// one 64-lane wave per node, each lane owns a bf16 pair (128 feats)
__global__ __launch_bounds__(256) void k_agg1(const unsigned short* __restrict__ H, const int* __restrict__ csr,
                                              const int* __restrict__ offs, const float* __restrict__ dinv,
                                              const float* __restrict__ b1, float* __restrict__ R){
  int gid = blockIdx.x * 256 + threadIdx.x;
  int node = gid >> 6;
  int lane = threadIdx.x & 63;
  if (node >= NN) return;
  int e0 = offs[node], e1 = offs[node + 1];
  float a0 = 0.f, a1 = 0.f;
  int e = e0;
  for (; e + 2 <= e1; e += 2){
    int s0 = __builtin_amdgcn_readfirstlane(csr[e]);
    int s1 = __builtin_amdgcn_readfirstlane(csr[e + 1]);
    uint32_t v0 = *(const uint32_t*)(H + (size_t)s0 * 128 + lane * 2);
    uint32_t v1 = *(const uint32_t*)(H + (size_t)s1 * 128 + lane * 2);
    a0 += bf_lo(v0) + bf_lo(v1);
    a1 += bf_hi(v0) + bf_hi(v1);
  }
  if (e < e1){
    int s0 = __builtin_amdgcn_readfirstlane(csr[e]);
    uint32_t v0 = *(const uint32_t*)(H + (size_t)s0 * 128 + lane * 2);
    a0 += bf_lo(v0); a1 += bf_hi(v0);
  }
  { // self loop
    uint32_t v = *(const uint32_t*)(H + (size_t)node * 128 + lane * 2);
    a0 += bf_lo(v); a1 += bf_hi(v);
  }
  float dv = dinv[node];
  float2 o; o.x = a0 * dv + b1[lane * 2]; o.y = a1 * dv + b1[lane * 2 + 1];
  *(float2*)&R[(size_t)node * 128 + lane * 2] = o;
}

// ---------------- aggregation 2: 64 feats, one 32-lane half-wave per node ----------------
__global__ __launch_bounds__(256) void k_agg2(const unsigned short* __restrict__ H, const int* __restrict__ csr,
                                              const int* __restrict__ offs, const float* __restrict__ dinv,
                                              const float* __restrict__ b2, float* __restrict__ R){
  int gid = blockIdx.x * 256 + threadIdx.x;
  int node = gid >> 5;
  int lane = threadIdx.x & 31;
  if (node >= NN) return;
  int e0 = offs[node], e1 = offs[node + 1];
  float a0 = 0.f, a1 = 0.f;
  int e = e0;
  for (; e + 2 <= e1; e += 2){
    int s0 = csr[e];
    int s1 = csr[e + 1];
    uint32_t v0 = *(const uint32_t*)(H + (size_t)s0 * 64 + lane * 2);
    uint32_t v1 = *(const uint32_t*)(H + (size_t)s1 * 64 + lane * 2);
    a0 += bf_lo(v0) + bf_lo(v1);
    a1 += bf_hi(v0) + bf_hi(v1);
  }
  if (e < e1){
    int s0 = csr[e];
    uint32_t v0 = *(const uint32_t*)(H + (size_t)s0 * 64 + lane * 2);
    a0 += bf_lo(v0); a1 += bf_hi(v0);
  }
  {
    uint32_t v = *(const uint32_t*)(H + (size_t)node * 64 + lane * 2);
    a0 += bf_lo(v); a1 += bf_hi(v);
  }
  float dv = dinv[node];
  float2 o; o.x = a0 * dv + b2[lane * 2]; o.y = a1 * dv + b2[lane * 2 + 1];
  *(float2*)&R[(size_t)node * 64 + lane * 2] = o;
}

// ---------------- classifier: out = res2 @ Wc + bc ----------------
__global__ __launch_bounds__(256) void k_gemm3(const float* __restrict__ A, const float* __restrict__ W,
                                               const float* __restrict__ bc, float* __restrict__ O){
  __shared__ float w[512];
  __shared__ float bb[8];
  int tid = threadIdx.x;
  if (tid < 8) bb[tid] = bc[tid];
  for (int i = tid; i < 512; i += 256) w[i] = W[i];
  __syncthreads();
  int r = blockIdx.x * 256 + tid;
  if (r >= NN) return;
  float acc[8] = {};
  for (int k = 0; k < 64; k += 4){
    float4 a = *(const float4*)&A[(size_t)r * 64 + k];
    #pragma unroll
    for (int j = 0; j < 8; ++j){
      acc[j] += a.x * w[k*8 + j] + a.y * w[(k+1)*8 + j] + a.z * w[(k+2)*8 + j] + a.w * w[(k+3)*8 + j];
    }
  }
  float4 o0, o1;
  o0.x = acc[0]+bb[0]; o0.y = acc[1]+bb[1]; o0.z = acc[2]+bb[2]; o0.w = acc[3]+bb[3];
  o1.x = acc[4]+bb[4]; o1.y = acc[5]+bb[5]; o1.z = acc[6]+bb[6]; o1.w = acc[7]+bb[7];
  *(float4*)&O[(size_t)r * 8 + 0] = o0;
  *(float4*)&O[(size_t)r * 8 + 4] = o1;
}

extern "C" void kernel_launch(void* const* d_in, const int* in_sizes, int n_in,
                              void* d_out, int out_size, void* d_ws, size_t ws_size,
                              hipStream_t stream) {
  const float* seq = (const float*)d_in[0];
  const int*   ei  = (const int*)d_in[1];
  const int*   esrc = ei;
  const int*   edst = ei + NE;
  const float* W1 = (const float*)d_in[2];
  const float* b1 = (const float*)d_in[3];
  const float* W2 = (const float*)d_in[4];
  const float* b2 = (const float*)d_in[5];
  const float* Wc = (const float*)d_in[6];
  const float* bc = (const float*)d_in[7];
  float* out = (float*)d_out;

  char* ws = (char*)d_ws;
  size_t o = 0;
  auto alloc = [&](size_t bytes) -> void* {
    void* p = ws + o;
    o += (bytes + 255) & ~(size_t)255;
    return p;
  };
  int*   deg  = (int*)alloc((size_t)NN * 4);
  int*   ctr  = (int*)alloc((size_t)NN * 4);
  float* dinv = (float*)alloc((size_t)NN * 4);
  int*   offs = (int*)alloc((size_t)(NN + 1) * 4);
  int*   bsum = (int*)alloc(64 * 4);
  int*   csr  = (int*)alloc((size_t)NE * 4);
  unsigned short* hbuf = (unsigned short*)alloc((size_t)NN * 128 * 2); // h1s, later h2s
  float* rbuf = (float*)alloc((size_t)NN * 128 * 4);                   // res1, later res2

  hipMemsetAsync(deg, 0, (size_t)NN * 4, stream);
  hipMemsetAsync(ctr, 0, (size_t)NN * 4, stream);

  const int nb = (NN + 1023) / 1024;
  k_count<<<(NE + 255) / 256, 256, 0, stream>>>(edst, deg);
  k_dinv <<<(NN + 255) / 256, 256, 0, stream>>>(deg, dinv);
  k_scan1<<<nb, 1024, 0, stream>>>(deg, offs, bsum);
  k_scan2<<<1, 64, 0, stream>>>(bsum, offs, nb);
  k_scan3<<<nb, 1024, 0, stream>>>(offs, bsum);
  k_fill <<<(NE + 255) / 256, 256, 0, stream>>>(esrc, edst, offs, ctr, csr);

  k_gemm1<<<(NN + 31) / 32, 256, 0, stream>>>(seq, W1, dinv, hbuf);
  k_agg1 <<<(NN * 64) / 256, 256, 0, stream>>>(hbuf, csr, offs, dinv, b1, rbuf);
  k_gemm2<<<(NN + 31) / 32, 256, 0, stream>>>(rbuf, W2, dinv, hbuf);
  k_agg2 <<<(NN * 32) / 256, 256, 0, stream>>>(hbuf, csr, offs, dinv, b2, rbuf);
  k_gemm3<<<(NN + 255) / 256, 256, 0, stream>>>(rbuf, Wc, bc, out);
}

// Round 2
// 388.225 us; speedup vs baseline: 1.2081x; 1.2081x over previous
//
#include <hip/hip_runtime.h>
#include <hip/hip_bf16.h>
#include <stdint.h>

#define NN 50000
#define NE 1600000

typedef short bf16x8 __attribute__((ext_vector_type(8)));
typedef float f32x4  __attribute__((ext_vector_type(4)));

__device__ __forceinline__ float bf_lo(uint32_t v){ return __uint_as_float(v << 16); }
__device__ __forceinline__ float bf_hi(uint32_t v){ return __uint_as_float(v & 0xffff0000u); }
__device__ __forceinline__ unsigned short f2bf(float f){
  uint32_t u = __float_as_uint(f);
  uint32_t r = (u + 0x7fffu + ((u >> 16) & 1u)) >> 16;   // RNE
  return (unsigned short)r;
}
// split helpers: hi = truncated bf16, lo = bf16(a - hi)
__device__ __forceinline__ uint32_t pack_hi(float x, float y){
  return (__float_as_uint(x) >> 16) | (__float_as_uint(y) & 0xffff0000u);
}
__device__ __forceinline__ float trunc_hi(float x){
  return __uint_as_float(__float_as_uint(x) & 0xffff0000u);
}

union FragU { uint32_t u[4]; bf16x8 v; };

// ---------------- graph preprocessing ----------------
__global__ void k_count(const int* __restrict__ dst, int* __restrict__ deg){
  int i = blockIdx.x * 256 + threadIdx.x;
  if (i < NE) atomicAdd(&deg[dst[i]], 1);
}

__global__ void k_dinv(const int* __restrict__ deg, float* __restrict__ dinv){
  int i = blockIdx.x * 256 + threadIdx.x;
  if (i < NN) dinv[i] = rsqrtf((float)(deg[i] + 1));   // +1 self-loop
}

__global__ void k_scan1(const int* __restrict__ deg, int* __restrict__ offs, int* __restrict__ bsum){
  __shared__ int lds[1024];
  int i = blockIdx.x * 1024 + threadIdx.x;
  int v = (i < NN) ? deg[i] : 0;
  lds[threadIdx.x] = v;
  __syncthreads();
  for (int ofs = 1; ofs < 1024; ofs <<= 1){
    int t = (threadIdx.x >= ofs) ? lds[threadIdx.x - ofs] : 0;
    __syncthreads();
    lds[threadIdx.x] += t;
    __syncthreads();
  }
  if (i < NN) offs[i] = lds[threadIdx.x] - v;
  if (threadIdx.x == 1023) bsum[blockIdx.x] = lds[1023];
}

__global__ void k_scan2(int* __restrict__ bsum, int* __restrict__ offs, int nb){
  if (blockIdx.x == 0 && threadIdx.x == 0){
    int run = 0;
    for (int b = 0; b < nb; ++b){ int t = bsum[b]; bsum[b] = run; run += t; }
    offs[NN] = run;
  }
}

__global__ void k_scan3(int* __restrict__ offs, const int* __restrict__ bsum){
  int i = blockIdx.x * 1024 + threadIdx.x;
  if (i < NN) offs[i] += bsum[blockIdx.x];
}

__global__ void k_fill(const int* __restrict__ src, const int* __restrict__ dst,
                       const int* __restrict__ offs, int* __restrict__ ctr, int* __restrict__ csr){
  int e = blockIdx.x * 256 + threadIdx.x;
  if (e < NE){
    int d = dst[e];
    int p = atomicAdd(&ctr[d], 1);
    csr[offs[d] + p] = src[e];
  }
}

// ---------------- weight split: W [K][N] fp32 -> Bh/Bl transposed [N][Kpad] bf16 ----------------
__global__ void k_bsplit(const float* __restrict__ W, unsigned short* __restrict__ Bh,
                         unsigned short* __restrict__ Bl, int K, int N, int Kpad){
  int i = blockIdx.x * 256 + threadIdx.x;
  if (i >= K * N) return;
  int k = i / N, n = i % N;
  float a = W[i];
  uint32_t hb = __float_as_uint(a) >> 16;                 // truncated hi
  float hf = __uint_as_float(hb << 16);
  uint32_t lb = __float_as_uint(a - hf) >> 16;            // truncated lo
  Bh[n * Kpad + k] = (unsigned short)hb;
  Bl[n * Kpad + k] = (unsigned short)lb;
}

// ---------------- GEMM1 (MFMA): H = bf16( (A @ W1) * dinv[row] ) ----------------
// A [NN,256] fp32, Bh/Bl [128][264] bf16 (transposed W1 hi/lo), H [NN,128] bf16
// block: 256 thr = 4 waves x 16 rows = 64 rows; per wave: 8 N-tiles of 16
__global__ __launch_bounds__(256) void k_gemm1(const float* __restrict__ A,
                                               const unsigned short* __restrict__ Bh,
                                               const unsigned short* __restrict__ Bl,
                                               const float* __restrict__ dinv,
                                               unsigned short* __restrict__ H){
  __shared__ unsigned short lb_h[128 * 72];
  __shared__ unsigned short lb_l[128 * 72];
  const int tid = threadIdx.x;
  const int lane = tid & 63;
  const int wv = tid >> 6;
  const int lrow = lane & 15;
  const int lk = (lane >> 4) * 8;

  int arow = blockIdx.x * 64 + wv * 16 + lrow;
  int arow_c = arow < NN ? arow : NN - 1;
  const float* Ap = A + (size_t)arow_c * 256 + lk;

  float4 areg[16];
  #pragma unroll
  for (int c = 0; c < 8; ++c){
    areg[2*c]   = *(const float4*)(Ap + c * 32);
    areg[2*c+1] = *(const float4*)(Ap + c * 32 + 4);
  }

  f32x4 acc[8];
  #pragma unroll
  for (int t = 0; t < 8; ++t){ f32x4 z = {0.f,0.f,0.f,0.f}; acc[t] = z; }

  #pragma unroll
  for (int s = 0; s < 4; ++s){
    const int kb = s * 64;
    if (s) __syncthreads();
    // stage 64-k slice of Bh/Bl -> LDS [128][72]
    #pragma unroll
    for (int i = 0; i < 4; ++i){
      int c = tid + i * 256;            // 0..1023
      int n = c >> 3, off = (c & 7) * 8;
      *(uint4*)&lb_h[n * 72 + off] = *(const uint4*)&Bh[n * 264 + kb + off];
      *(uint4*)&lb_l[n * 72 + off] = *(const uint4*)&Bl[n * 264 + kb + off];
    }
    __syncthreads();
    #pragma unroll
    for (int h2 = 0; h2 < 2; ++h2){
      const int c = s * 2 + h2;
      float4 X = areg[2*c], Y = areg[2*c+1];
      FragU uh, ul;
      uh.u[0] = pack_hi(X.x, X.y); uh.u[1] = pack_hi(X.z, X.w);
      uh.u[2] = pack_hi(Y.x, Y.y); uh.u[3] = pack_hi(Y.z, Y.w);
      ul.u[0] = pack_hi(X.x - trunc_hi(X.x), X.y - trunc_hi(X.y));
      ul.u[1] = pack_hi(X.z - trunc_hi(X.z), X.w - trunc_hi(X.w));
      ul.u[2] = pack_hi(Y.x - trunc_hi(Y.x), Y.y - trunc_hi(Y.y));
      ul.u[3] = pack_hi(Y.z - trunc_hi(Y.z), Y.w - trunc_hi(Y.w));
      const int kidx = h2 * 32 + lk;
      #pragma unroll
      for (int t = 0; t < 8; ++t){
        bf16x8 bh = *(const bf16x8*)&lb_h[(t * 16 + lrow) * 72 + kidx];
        bf16x8 bl = *(const bf16x8*)&lb_l[(t * 16 + lrow) * 72 + kidx];
        acc[t] = __builtin_amdgcn_mfma_f32_16x16x32_bf16(uh.v, bh, acc[t], 0, 0, 0);
        acc[t] = __builtin_amdgcn_mfma_f32_16x16x32_bf16(ul.v, bh, acc[t], 0, 0, 0);
        acc[t] = __builtin_amdgcn_mfma_f32_16x16x32_bf16(uh.v, bl, acc[t], 0, 0, 0);
      }
    }
  }

  // epilogue: D col = lane&15, row = (lane>>4)*4 + reg
  const int rb = blockIdx.x * 64 + wv * 16 + (lane >> 4) * 4;
  float sc[4];
  #pragma unroll
  for (int r = 0; r < 4; ++r){
    int rr = rb + r; sc[r] = dinv[rr < NN ? rr : NN - 1];
  }
  #pragma unroll
  for (int t = 0; t < 8; ++t){
    #pragma unroll
    for (int r = 0; r < 4; ++r){
      int row = rb + r;
      if (row < NN) H[(size_t)row * 128 + t * 16 + lrow] = f2bf(acc[t][r] * sc[r]);
    }
  }
}

// ---------------- GEMM2 (MFMA): H2 = bf16( (res1 @ W2) * dinv[row] ) ----------------
// A [NN,128] fp32, Bh/Bl [64][136] bf16, H2 [NN,64] bf16
__global__ __launch_bounds__(256) void k_gemm2(const float* __restrict__ A,
                                               const unsigned short* __restrict__ Bh,
                                               const unsigned short* __restrict__ Bl,
                                               const float* __restrict__ dinv,
                                               unsigned short* __restrict__ H){
  __shared__ unsigned short lb_h[64 * 136];
  __shared__ unsigned short lb_l[64 * 136];
  const int tid = threadIdx.x;
  const int lane = tid & 63;
  const int wv = tid >> 6;
  const int lrow = lane & 15;
  const int lk = (lane >> 4) * 8;

  int arow = blockIdx.x * 64 + wv * 16 + lrow;
  int arow_c = arow < NN ? arow : NN - 1;
  const float* Ap = A + (size_t)arow_c * 128 + lk;

  float4 areg[8];
  #pragma unroll
  for (int c = 0; c < 4; ++c){
    areg[2*c]   = *(const float4*)(Ap + c * 32);
    areg[2*c+1] = *(const float4*)(Ap + c * 32 + 4);
  }

  // stage full K=128 of Bh/Bl (identical padded layout as global: [64][136])
  #pragma unroll
  for (int i = 0; i < 4; ++i){
    int c = tid + i * 256;              // 0..1023
    int n = c >> 4, off = (c & 15) * 8;
    *(uint4*)&lb_h[n * 136 + off] = *(const uint4*)&Bh[n * 136 + off];
    *(uint4*)&lb_l[n * 136 + off] = *(const uint4*)&Bl[n * 136 + off];
  }
  __syncthreads();

  f32x4 acc[4];
  #pragma unroll
  for (int t = 0; t < 4; ++t){ f32x4 z = {0.f,0.f,0.f,0.f}; acc[t] = z; }

  #pragma unroll
  for (int c = 0; c < 4; ++c){
    float4 X = areg[2*c], Y = areg[2*c+1];
    FragU uh, ul;
    uh.u[0] = pack_hi(X.x, X.y); uh.u[1] = pack_hi(X.z, X.w);
    uh.u[2] = pack_hi(Y.x, Y.y); uh.u[3] = pack_hi(Y.z, Y.w);
    ul.u[0] = pack_hi(X.x - trunc_hi(X.x), X.y - trunc_hi(X.y));
    ul.u[1] = pack_hi(X.z - trunc_hi(X.z), X.w - trunc_hi(X.w));
    ul.u[2] = pack_hi(Y.x - trunc_hi(Y.x), Y.y - trunc_hi(Y.y));
    ul.u[3] = pack_hi(Y.z - trunc_hi(Y.z), Y.w - trunc_hi(Y.w));
    const int kidx = c * 32 + lk;
    #pragma unroll
    for (int t = 0; t < 4; ++t){
      bf16x8 bh = *(const bf16x8*)&lb_h[(t * 16 + lrow) * 136 + kidx];
      bf16x8 bl = *(const bf16x8*)&lb_l[(t * 16 + lrow) * 136 + kidx];
      acc[t] = __builtin_amdgcn_mfma_f32_16x16x32_bf16(uh.v, bh, acc[t], 0, 0, 0);
      acc[t] = __builtin_amdgcn_mfma_f32_16x16x32_bf16(ul.v, bh, acc[t], 0, 0, 0);
      acc[t] = __builtin_amdgcn_mfma_f32_16x16x32_bf16(uh.v, bl, acc[t], 0, 0, 0);
    }
  }

  const int rb = blockIdx.x * 64 + wv * 16 + (lane >> 4) * 4;
  float sc[4];
  #pragma unroll
  for (int r = 0; r < 4; ++r){
    int rr = rb + r; sc[r] = dinv[rr < NN ? rr : NN - 1];
  }
  #pragma unroll
  for (int t = 0; t < 4; ++t){
    #pragma unroll
    for (int r = 0; r < 4; ++r){
      int row = rb + r;
      if (row < NN) H[(size_t)row * 64 + t * 16 + lrow] = f2bf(acc[t][r] * sc[r]);
    }
  }
}

// ---------------- aggregation 1: res1 = dinv*(h1s[self] + sum h1s[src]) + b1 ----------------
__global__ __launch_bounds__(256) void k_agg1(const unsigned short* __restrict__ H, const int* __restrict__ csr,
                                              const int* __restrict__ offs, const float* __restrict__ dinv,
                                              const float* __restrict__ b1, float* __restrict__ R){
  int gid = blockIdx.x * 256 + threadIdx.x;
  int node = gid >> 6;
  int lane = threadIdx.x & 63;
  if (node >= NN) return;
  int e0 = offs[node], e1 = offs[node + 1];
  float a0 = 0.f, a1 = 0.f;
  int e = e0;
  for (; e + 2 <= e1; e += 2){
    int s0 = __builtin_amdgcn_readfirstlane(csr[e]);
    int s1 = __builtin_amdgcn_readfirstlane(csr[e + 1]);
    uint32_t v0 = *(const uint32_t*)(H + (size_t)s0 * 128 + lane * 2);
    uint32_t v1 = *(const uint32_t*)(H + (size_t)s1 * 128 + lane * 2);
    a0 += bf_lo(v0) + bf_lo(v1);
    a1 += bf_hi(v0) + bf_hi(v1);
  }
  if (e < e1){
    int s0 = __builtin_amdgcn_readfirstlane(csr[e]);
    uint32_t v0 = *(const uint32_t*)(H + (size_t)s0 * 128 + lane * 2);
    a0 += bf_lo(v0); a1 += bf_hi(v0);
  }
  {
    uint32_t v = *(const uint32_t*)(H + (size_t)node * 128 + lane * 2);
    a0 += bf_lo(v); a1 += bf_hi(v);
  }
  float dv = dinv[node];
  float2 o; o.x = a0 * dv + b1[lane * 2]; o.y = a1 * dv + b1[lane * 2 + 1];
  *(float2*)&R[(size_t)node * 128 + lane * 2] = o;
}

// ---------------- aggregation 2: 64 feats, one 32-lane half-wave per node ----------------
__global__ __launch_bounds__(256) void k_agg2(const unsigned short* __restrict__ H, const int* __restrict__ csr,
                                              const int* __restrict__ offs, const float* __restrict__ dinv,
                                              const float* __restrict__ b2, float* __restrict__ R){
  int gid = blockIdx.x * 256 + threadIdx.x;
  int node = gid >> 5;
  int lane = threadIdx.x & 31;
  if (node >= NN) return;
  int e0 = offs[node], e1 = offs[node + 1];
  float a0 = 0.f, a1 = 0.f;
  int e = e0;
  for (; e + 2 <= e1; e += 2){
    int s0 = csr[e];
    int s1 = csr[e + 1];
    uint32_t v0 = *(const uint32_t*)(H + (size_t)s0 * 64 + lane * 2);
    uint32_t v1 = *(const uint32_t*)(H + (size_t)s1 * 64 + lane * 2);
    a0 += bf_lo(v0) + bf_lo(v1);
    a1 += bf_hi(v0) + bf_hi(v1);
  }
  if (e < e1){
    int s0 = csr[e];
    uint32_t v0 = *(const uint32_t*)(H + (size_t)s0 * 64 + lane * 2);
    a0 += bf_lo(v0); a1 += bf_hi(v0);
  }
  {
    uint32_t v = *(const uint32_t*)(H + (size_t)node * 64 + lane * 2);
    a0 += bf_lo(v); a1 += bf_hi(v);
  }
  float dv = dinv[node];
  float2 o; o.x = a0 * dv + b2[lane * 2]; o.y = a1 * dv + b2[lane * 2 + 1];
  *(float2*)&R[(size_t)node * 64 + lane * 2] = o;
}

// ---------------- classifier: out = res2 @ Wc + bc ----------------
__global__ __launch_bounds__(256) void k_gemm3(const float* __restrict__ A, const float* __restrict__ W,
                                               const float* __restrict__ bc, float* __restrict__ O){
  __shared__ float w[512];
  __shared__ float bb[8];
  int tid = threadIdx.x;
  if (tid < 8) bb[tid] = bc[tid];
  for (int i = tid; i < 512; i += 256) w[i] = W[i];
  __syncthreads();
  int r = blockIdx.x * 256 + tid;
  if (r >= NN) return;
  float acc[8] = {};
  for (int k = 0; k < 64; k += 4){
    float4 a = *(const float4*)&A[(size_t)r * 64 + k];
    #pragma unroll
    for (int j = 0; j < 8; ++j){
      acc[j] += a.x * w[k*8 + j] + a.y * w[(k+1)*8 + j] + a.z * w[(k+2)*8 + j] + a.w * w[(k+3)*8 + j];
    }
  }
  float4 o0, o1;
  o0.x = acc[0]+bb[0]; o0.y = acc[1]+bb[1]; o0.z = acc[2]+bb[2]; o0.w = acc[3]+bb[3];
  o1.x = acc[4]+bb[4]; o1.y = acc[5]+bb[5]; o1.z = acc[6]+bb[6]; o1.w = acc[7]+bb[7];
  *(float4*)&O[(size_t)r * 8 + 0] = o0;
  *(float4*)&O[(size_t)r * 8 + 4] = o1;
}

extern "C" void kernel_launch(void* const* d_in, const int* in_sizes, int n_in,
                              void* d_out, int out_size, void* d_ws, size_t ws_size,
                              hipStream_t stream) {
  const float* seq = (const float*)d_in[0];
  const int*   ei  = (const int*)d_in[1];
  const int*   esrc = ei;
  const int*   edst = ei + NE;
  const float* W1 = (const float*)d_in[2];
  const float* b1 = (const float*)d_in[3];
  const float* W2 = (const float*)d_in[4];
  const float* b2 = (const float*)d_in[5];
  const float* Wc = (const float*)d_in[6];
  const float* bc = (const float*)d_in[7];
  float* out = (float*)d_out;

  char* ws = (char*)d_ws;
  size_t o = 0;
  auto alloc = [&](size_t bytes) -> void* {
    void* p = ws + o;
    o += (bytes + 255) & ~(size_t)255;
    return p;
  };
  int*   deg  = (int*)alloc((size_t)NN * 4);
  int*   ctr  = (int*)alloc((size_t)NN * 4);
  float* dinv = (float*)alloc((size_t)NN * 4);
  int*   offs = (int*)alloc((size_t)(NN + 1) * 4);
  int*   bsum = (int*)alloc(64 * 4);
  int*   csr  = (int*)alloc((size_t)NE * 4);
  unsigned short* hbuf = (unsigned short*)alloc((size_t)NN * 128 * 2); // h1s, later h2s
  float* rbuf = (float*)alloc((size_t)NN * 128 * 4);                   // res1, later res2
  unsigned short* B1h = (unsigned short*)alloc((size_t)128 * 264 * 2);
  unsigned short* B1l = (unsigned short*)alloc((size_t)128 * 264 * 2);
  unsigned short* B2h = (unsigned short*)alloc((size_t)64 * 136 * 2);
  unsigned short* B2l = (unsigned short*)alloc((size_t)64 * 136 * 2);

  hipMemsetAsync(deg, 0, (size_t)NN * 4, stream);
  hipMemsetAsync(ctr, 0, (size_t)NN * 4, stream);

  const int nb = (NN + 1023) / 1024;
  k_count<<<(NE + 255) / 256, 256, 0, stream>>>(edst, deg);
  k_dinv <<<(NN + 255) / 256, 256, 0, stream>>>(deg, dinv);
  k_scan1<<<nb, 1024, 0, stream>>>(deg, offs, bsum);
  k_scan2<<<1, 64, 0, stream>>>(bsum, offs, nb);
  k_scan3<<<nb, 1024, 0, stream>>>(offs, bsum);
  k_fill <<<(NE + 255) / 256, 256, 0, stream>>>(esrc, edst, offs, ctr, csr);

  k_bsplit<<<(256 * 128 + 255) / 256, 256, 0, stream>>>(W1, B1h, B1l, 256, 128, 264);
  k_bsplit<<<(128 * 64 + 255) / 256, 256, 0, stream>>>(W2, B2h, B2l, 128, 64, 136);

  const int gblocks = (NN + 63) / 64;
  k_gemm1<<<gblocks, 256, 0, stream>>>(seq, B1h, B1l, dinv, hbuf);
  k_agg1 <<<(NN * 64) / 256, 256, 0, stream>>>(hbuf, csr, offs, dinv, b1, rbuf);
  k_gemm2<<<gblocks, 256, 0, stream>>>(rbuf, B2h, B2l, dinv, hbuf);
  k_agg2 <<<(NN * 32) / 256, 256, 0, stream>>>(hbuf, csr, offs, dinv, b2, rbuf);
  k_gemm3<<<(NN + 255) / 256, 256, 0, stream>>>(rbuf, Wc, bc, out);
}

// Round 3
// 255.087 us; speedup vs baseline: 1.8387x; 1.5219x over previous
//
#include <hip/hip_runtime.h>
#include <hip/hip_bf16.h>
#include <stdint.h>

#define NN 50000
#define NE 1600000
#define NBK 196          // number of dst buckets = (NN+255)>>8
#define NSB 512          // scatter blocks
#define ECH 3125         // edges per scatter block = NE/NSB

typedef short bf16x8 __attribute__((ext_vector_type(8)));
typedef float f32x4  __attribute__((ext_vector_type(4)));

__device__ __forceinline__ float bf_lo(uint32_t v){ return __uint_as_float(v << 16); }
__device__ __forceinline__ float bf_hi(uint32_t v){ return __uint_as_float(v & 0xffff0000u); }
__device__ __forceinline__ unsigned short f2bf(float f){
  uint32_t u = __float_as_uint(f);
  uint32_t r = (u + 0x7fffu + ((u >> 16) & 1u)) >> 16;   // RNE
  return (unsigned short)r;
}
__device__ __forceinline__ uint32_t pack_hi(float x, float y){
  return (__float_as_uint(x) >> 16) | (__float_as_uint(y) & 0xffff0000u);
}
__device__ __forceinline__ float trunc_hi(float x){
  return __uint_as_float(__float_as_uint(x) & 0xffff0000u);
}

union FragU { uint32_t u[4]; bf16x8 v; };

// ---------------- bucketed CSR build ----------------
// pass A: per-block bucket histogram
__global__ __launch_bounds__(256) void k_hist(const int* __restrict__ dst, int* __restrict__ bh){
  __shared__ int h[NBK];
  for (int i = threadIdx.x; i < NBK; i += 256) h[i] = 0;
  __syncthreads();
  int e0 = blockIdx.x * ECH;
  int e1 = e0 + ECH; if (e1 > NE) e1 = NE;
  for (int e = e0 + threadIdx.x; e < e1; e += 256)
    atomicAdd(&h[dst[e] >> 8], 1);
  __syncthreads();
  for (int i = threadIdx.x; i < NBK; i += 256)
    bh[i * NSB + blockIdx.x] = h[i];
}

// per-bucket exclusive scan across the NSB blocks
__global__ __launch_bounds__(512) void k_bscan(const int* __restrict__ bh, int* __restrict__ boff,
                                               int* __restrict__ btot){
  __shared__ int lds[NSB];
  int b = blockIdx.x;
  int v = bh[b * NSB + threadIdx.x];
  lds[threadIdx.x] = v;
  __syncthreads();
  for (int ofs = 1; ofs < NSB; ofs <<= 1){
    int t = (threadIdx.x >= ofs) ? lds[threadIdx.x - ofs] : 0;
    __syncthreads();
    lds[threadIdx.x] += t;
    __syncthreads();
  }
  boff[b * NSB + threadIdx.x] = lds[threadIdx.x] - v;
  if (threadIdx.x == NSB - 1) btot[b] = lds[NSB - 1];
}

// exclusive scan of bucket totals
__global__ __launch_bounds__(256) void k_btscan(const int* __restrict__ btot, int* __restrict__ bbase){
  __shared__ int lds[256];
  int v = (threadIdx.x < NBK) ? btot[threadIdx.x] : 0;
  lds[threadIdx.x] = v;
  __syncthreads();
  for (int ofs = 1; ofs < 256; ofs <<= 1){
    int t = (threadIdx.x >= ofs) ? lds[threadIdx.x - ofs] : 0;
    __syncthreads();
    lds[threadIdx.x] += t;
    __syncthreads();
  }
  if (threadIdx.x < NBK) bbase[threadIdx.x] = lds[threadIdx.x] - v;
  if (threadIdx.x == NBK - 1) bbase[NBK] = lds[threadIdx.x];
}

// pass B: scatter packed (src<<16 | dst) into bucket-sorted ebuf
__global__ __launch_bounds__(256) void k_scatter(const int* __restrict__ src, const int* __restrict__ dst,
                                                 const int* __restrict__ bbase, const int* __restrict__ boff,
                                                 uint32_t* __restrict__ ebuf){
  __shared__ int ctr[NBK];
  for (int i = threadIdx.x; i < NBK; i += 256)
    ctr[i] = bbase[i] + boff[i * NSB + blockIdx.x];
  __syncthreads();
  int e0 = blockIdx.x * ECH;
  int e1 = e0 + ECH; if (e1 > NE) e1 = NE;
  for (int e = e0 + threadIdx.x; e < e1; e += 256){
    int d = dst[e];
    int s = src[e];
    int p = atomicAdd(&ctr[d >> 8], 1);
    ebuf[p] = ((uint32_t)s << 16) | (uint32_t)d;
  }
}

// per-bucket degree histogram (+ dinv), LDS atomics, coalesced writes
__global__ __launch_bounds__(256) void k_bdeg(const uint32_t* __restrict__ ebuf, const int* __restrict__ bbase,
                                              int* __restrict__ deg, float* __restrict__ dinv){
  __shared__ int h[256];
  h[threadIdx.x] = 0;
  __syncthreads();
  int b = blockIdx.x;
  int e0 = bbase[b], e1 = bbase[b + 1];
  for (int e = e0 + threadIdx.x; e < e1; e += 256)
    atomicAdd(&h[ebuf[e] & 255], 1);
  __syncthreads();
  int node = (b << 8) + threadIdx.x;
  if (node < NN){
    int d = h[threadIdx.x];
    deg[node] = d;
    dinv[node] = rsqrtf((float)(d + 1));   // +1 self-loop
  }
}

// node-degree scans -> offs
__global__ void k_scan1(const int* __restrict__ deg, int* __restrict__ offs, int* __restrict__ bsum){
  __shared__ int lds[1024];
  int i = blockIdx.x * 1024 + threadIdx.x;
  int v = (i < NN) ? deg[i] : 0;
  lds[threadIdx.x] = v;
  __syncthreads();
  for (int ofs = 1; ofs < 1024; ofs <<= 1){
    int t = (threadIdx.x >= ofs) ? lds[threadIdx.x - ofs] : 0;
    __syncthreads();
    lds[threadIdx.x] += t;
    __syncthreads();
  }
  if (i < NN) offs[i] = lds[threadIdx.x] - v;
  if (threadIdx.x == 1023) bsum[blockIdx.x] = lds[1023];
}

__global__ void k_scan2(int* __restrict__ bsum, int* __restrict__ offs, int nb){
  if (blockIdx.x == 0 && threadIdx.x == 0){
    int run = 0;
    for (int b = 0; b < nb; ++b){ int t = bsum[b]; bsum[b] = run; run += t; }
    offs[NN] = run;
  }
}

__global__ void k_scan3(int* __restrict__ offs, const int* __restrict__ bsum){
  int i = blockIdx.x * 1024 + threadIdx.x;
  if (i < NN) offs[i] += bsum[blockIdx.x];
}

// pass C: per-bucket CSR fill, LDS counters, writes confined to small window
__global__ __launch_bounds__(256) void k_fill2(const uint32_t* __restrict__ ebuf, const int* __restrict__ bbase,
                                               const int* __restrict__ offs, unsigned short* __restrict__ csr){
  __shared__ int ctr[256];
  int b = blockIdx.x;
  int node = (b << 8) + threadIdx.x;
  ctr[threadIdx.x] = (node < NN) ? offs[node] : 0;
  __syncthreads();
  int e0 = bbase[b], e1 = bbase[b + 1];
  for (int e = e0 + threadIdx.x; e < e1; e += 256){
    uint32_t v = ebuf[e];
    int p = atomicAdd(&ctr[v & 255], 1);
    csr[p] = (unsigned short)(v >> 16);
  }
}

// ---------------- weight split: W [K][N] fp32 -> Bh/Bl transposed [N][Kpad] bf16 ----------------
__global__ void k_bsplit(const float* __restrict__ W, unsigned short* __restrict__ Bh,
                         unsigned short* __restrict__ Bl, int K, int N, int Kpad){
  int i = blockIdx.x * 256 + threadIdx.x;
  if (i >= K * N) return;
  int k = i / N, n = i % N;
  float a = W[i];
  uint32_t hb = __float_as_uint(a) >> 16;
  float hf = __uint_as_float(hb << 16);
  uint32_t lb = __float_as_uint(a - hf) >> 16;
  Bh[n * Kpad + k] = (unsigned short)hb;
  Bl[n * Kpad + k] = (unsigned short)lb;
}

// ---------------- GEMM1 (MFMA): H = bf16( (A @ W1) * dinv[row] ) ----------------
__global__ __launch_bounds__(256) void k_gemm1(const float* __restrict__ A,
                                               const unsigned short* __restrict__ Bh,
                                               const unsigned short* __restrict__ Bl,
                                               const float* __restrict__ dinv,
                                               unsigned short* __restrict__ H){
  __shared__ unsigned short lb_h[128 * 72];
  __shared__ unsigned short lb_l[128 * 72];
  const int tid = threadIdx.x;
  const int lane = tid & 63;
  const int wv = tid >> 6;
  const int lrow = lane & 15;
  const int lk = (lane >> 4) * 8;

  int arow = blockIdx.x * 64 + wv * 16 + lrow;
  int arow_c = arow < NN ? arow : NN - 1;
  const float* Ap = A + (size_t)arow_c * 256 + lk;

  float4 areg[16];
  #pragma unroll
  for (int c = 0; c < 8; ++c){
    areg[2*c]   = *(const float4*)(Ap + c * 32);
    areg[2*c+1] = *(const float4*)(Ap + c * 32 + 4);
  }

  f32x4 acc[8];
  #pragma unroll
  for (int t = 0; t < 8; ++t){ f32x4 z = {0.f,0.f,0.f,0.f}; acc[t] = z; }

  #pragma unroll
  for (int s = 0; s < 4; ++s){
    const int kb = s * 64;
    if (s) __syncthreads();
    #pragma unroll
    for (int i = 0; i < 4; ++i){
      int c = tid + i * 256;
      int n = c >> 3, off = (c & 7) * 8;
      *(uint4*)&lb_h[n * 72 + off] = *(const uint4*)&Bh[n * 264 + kb + off];
      *(uint4*)&lb_l[n * 72 + off] = *(const uint4*)&Bl[n * 264 + kb + off];
    }
    __syncthreads();
    #pragma unroll
    for (int h2 = 0; h2 < 2; ++h2){
      const int c = s * 2 + h2;
      float4 X = areg[2*c], Y = areg[2*c+1];
      FragU uh, ul;
      uh.u[0] = pack_hi(X.x, X.y); uh.u[1] = pack_hi(X.z, X.w);
      uh.u[2] = pack_hi(Y.x, Y.y); uh.u[3] = pack_hi(Y.z, Y.w);
      ul.u[0] = pack_hi(X.x - trunc_hi(X.x), X.y - trunc_hi(X.y));
      ul.u[1] = pack_hi(X.z - trunc_hi(X.z), X.w - trunc_hi(X.w));
      ul.u[2] = pack_hi(Y.x - trunc_hi(Y.x), Y.y - trunc_hi(Y.y));
      ul.u[3] = pack_hi(Y.z - trunc_hi(Y.z), Y.w - trunc_hi(Y.w));
      const int kidx = h2 * 32 + lk;
      #pragma unroll
      for (int t = 0; t < 8; ++t){
        bf16x8 bh = *(const bf16x8*)&lb_h[(t * 16 + lrow) * 72 + kidx];
        bf16x8 bl = *(const bf16x8*)&lb_l[(t * 16 + lrow) * 72 + kidx];
        acc[t] = __builtin_amdgcn_mfma_f32_16x16x32_bf16(uh.v, bh, acc[t], 0, 0, 0);
        acc[t] = __builtin_amdgcn_mfma_f32_16x16x32_bf16(ul.v, bh, acc[t], 0, 0, 0);
        acc[t] = __builtin_amdgcn_mfma_f32_16x16x32_bf16(uh.v, bl, acc[t], 0, 0, 0);
      }
    }
  }

  const int rb = blockIdx.x * 64 + wv * 16 + (lane >> 4) * 4;
  float sc[4];
  #pragma unroll
  for (int r = 0; r < 4; ++r){
    int rr = rb + r; sc[r] = dinv[rr < NN ? rr : NN - 1];
  }
  #pragma unroll
  for (int t = 0; t < 8; ++t){
    #pragma unroll
    for (int r = 0; r < 4; ++r){
      int row = rb + r;
      if (row < NN) H[(size_t)row * 128 + t * 16 + lrow] = f2bf(acc[t][r] * sc[r]);
    }
  }
}

// ---------------- GEMM2 (MFMA): H2 = bf16( (res1 @ W2) * dinv[row] ) ----------------
__global__ __launch_bounds__(256) void k_gemm2(const float* __restrict__ A,
                                               const unsigned short* __restrict__ Bh,
                                               const unsigned short* __restrict__ Bl,
                                               const float* __restrict__ dinv,
                                               unsigned short* __restrict__ H){
  __shared__ unsigned short lb_h[64 * 136];
  __shared__ unsigned short lb_l[64 * 136];
  const int tid = threadIdx.x;
  const int lane = tid & 63;
  const int wv = tid >> 6;
  const int lrow = lane & 15;
  const int lk = (lane >> 4) * 8;

  int arow = blockIdx.x * 64 + wv * 16 + lrow;
  int arow_c = arow < NN ? arow : NN - 1;
  const float* Ap = A + (size_t)arow_c * 128 + lk;

  float4 areg[8];
  #pragma unroll
  for (int c = 0; c < 4; ++c){
    areg[2*c]   = *(const float4*)(Ap + c * 32);
    areg[2*c+1] = *(const float4*)(Ap + c * 32 + 4);
  }

  #pragma unroll
  for (int i = 0; i < 4; ++i){
    int c = tid + i * 256;
    int n = c >> 4, off = (c & 15) * 8;
    *(uint4*)&lb_h[n * 136 + off] = *(const uint4*)&Bh[n * 136 + off];
    *(uint4*)&lb_l[n * 136 + off] = *(const uint4*)&Bl[n * 136 + off];
  }
  __syncthreads();

  f32x4 acc[4];
  #pragma unroll
  for (int t = 0; t < 4; ++t){ f32x4 z = {0.f,0.f,0.f,0.f}; acc[t] = z; }

  #pragma unroll
  for (int c = 0; c < 4; ++c){
    float4 X = areg[2*c], Y = areg[2*c+1];
    FragU uh, ul;
    uh.u[0] = pack_hi(X.x, X.y); uh.u[1] = pack_hi(X.z, X.w);
    uh.u[2] = pack_hi(Y.x, Y.y); uh.u[3] = pack_hi(Y.z, Y.w);
    ul.u[0] = pack_hi(X.x - trunc_hi(X.x), X.y - trunc_hi(X.y));
    ul.u[1] = pack_hi(X.z - trunc_hi(X.z), X.w - trunc_hi(X.w));
    ul.u[2] = pack_hi(Y.x - trunc_hi(Y.x), Y.y - trunc_hi(Y.y));
    ul.u[3] = pack_hi(Y.z - trunc_hi(Y.z), Y.w - trunc_hi(Y.w));
    const int kidx = c * 32 + lk;
    #pragma unroll
    for (int t = 0; t < 4; ++t){
      bf16x8 bh = *(const bf16x8*)&lb_h[(t * 16 + lrow) * 136 + kidx];
      bf16x8 bl = *(const bf16x8*)&lb_l[(t * 16 + lrow) * 136 + kidx];
      acc[t] = __builtin_amdgcn_mfma_f32_16x16x32_bf16(uh.v, bh, acc[t], 0, 0, 0);
      acc[t] = __builtin_amdgcn_mfma_f32_16x16x32_bf16(ul.v, bh, acc[t], 0, 0, 0);
      acc[t] = __builtin_amdgcn_mfma_f32_16x16x32_bf16(uh.v, bl, acc[t], 0, 0, 0);
    }
  }

  const int rb = blockIdx.x * 64 + wv * 16 + (lane >> 4) * 4;
  float sc[4];
  #pragma unroll
  for (int r = 0; r < 4; ++r){
    int rr = rb + r; sc[r] = dinv[rr < NN ? rr : NN - 1];
  }
  #pragma unroll
  for (int t = 0; t < 4; ++t){
    #pragma unroll
    for (int r = 0; r < 4; ++r){
      int row = rb + r;
      if (row < NN) H[(size_t)row * 64 + t * 16 + lrow] = f2bf(acc[t][r] * sc[r]);
    }
  }
}

// ---------------- aggregation 1 ----------------
__global__ __launch_bounds__(256) void k_agg1(const unsigned short* __restrict__ H, const unsigned short* __restrict__ csr,
                                              const int* __restrict__ offs, const float* __restrict__ dinv,
                                              const float* __restrict__ b1, float* __restrict__ R){
  int gid = blockIdx.x * 256 + threadIdx.x;
  int node = gid >> 6;
  int lane = threadIdx.x & 63;
  if (node >= NN) return;
  int e0 = offs[node], e1 = offs[node + 1];
  float a0 = 0.f, a1 = 0.f;
  int e = e0;
  for (; e + 2 <= e1; e += 2){
    int s0 = __builtin_amdgcn_readfirstlane(csr[e]);
    int s1 = __builtin_amdgcn_readfirstlane(csr[e + 1]);
    uint32_t v0 = *(const uint32_t*)(H + (size_t)s0 * 128 + lane * 2);
    uint32_t v1 = *(const uint32_t*)(H + (size_t)s1 * 128 + lane * 2);
    a0 += bf_lo(v0) + bf_lo(v1);
    a1 += bf_hi(v0) + bf_hi(v1);
  }
  if (e < e1){
    int s0 = __builtin_amdgcn_readfirstlane(csr[e]);
    uint32_t v0 = *(const uint32_t*)(H + (size_t)s0 * 128 + lane * 2);
    a0 += bf_lo(v0); a1 += bf_hi(v0);
  }
  {
    uint32_t v = *(const uint32_t*)(H + (size_t)node * 128 + lane * 2);
    a0 += bf_lo(v); a1 += bf_hi(v);
  }
  float dv = dinv[node];
  float2 o; o.x = a0 * dv + b1[lane * 2]; o.y = a1 * dv + b1[lane * 2 + 1];
  *(float2*)&R[(size_t)node * 128 + lane * 2] = o;
}

// ---------------- aggregation 2 ----------------
__global__ __launch_bounds__(256) void k_agg2(const unsigned short* __restrict__ H, const unsigned short* __restrict__ csr,
                                              const int* __restrict__ offs, const float* __restrict__ dinv,
                                              const float* __restrict__ b2, float* __restrict__ R){
  int gid = blockIdx.x * 256 + threadIdx.x;
  int node = gid >> 5;
  int lane = threadIdx.x & 31;
  if (node >= NN) return;
  int e0 = offs[node], e1 = offs[node + 1];
  float a0 = 0.f, a1 = 0.f;
  int e = e0;
  for (; e + 2 <= e1; e += 2){
    int s0 = csr[e];
    int s1 = csr[e + 1];
    uint32_t v0 = *(const uint32_t*)(H + (size_t)s0 * 64 + lane * 2);
    uint32_t v1 = *(const uint32_t*)(H + (size_t)s1 * 64 + lane * 2);
    a0 += bf_lo(v0) + bf_lo(v1);
    a1 += bf_hi(v0) + bf_hi(v1);
  }
  if (e < e1){
    int s0 = csr[e];
    uint32_t v0 = *(const uint32_t*)(H + (size_t)s0 * 64 + lane * 2);
    a0 += bf_lo(v0); a1 += bf_hi(v0);
  }
  {
    uint32_t v = *(const uint32_t*)(H + (size_t)node * 64 + lane * 2);
    a0 += bf_lo(v); a1 += bf_hi(v);
  }
  float dv = dinv[node];
  float2 o; o.x = a0 * dv + b2[lane * 2]; o.y = a1 * dv + b2[lane * 2 + 1];
  *(float2*)&R[(size_t)node * 64 + lane * 2] = o;
}

// ---------------- classifier ----------------
__global__ __launch_bounds__(256) void k_gemm3(const float* __restrict__ A, const float* __restrict__ W,
                                               const float* __restrict__ bc, float* __restrict__ O){
  __shared__ float w[512];
  __shared__ float bb[8];
  int tid = threadIdx.x;
  if (tid < 8) bb[tid] = bc[tid];
  for (int i = tid; i < 512; i += 256) w[i] = W[i];
  __syncthreads();
  int r = blockIdx.x * 256 + tid;
  if (r >= NN) return;
  float acc[8] = {};
  for (int k = 0; k < 64; k += 4){
    float4 a = *(const float4*)&A[(size_t)r * 64 + k];
    #pragma unroll
    for (int j = 0; j < 8; ++j){
      acc[j] += a.x * w[k*8 + j] + a.y * w[(k+1)*8 + j] + a.z * w[(k+2)*8 + j] + a.w * w[(k+3)*8 + j];
    }
  }
  float4 o0, o1;
  o0.x = acc[0]+bb[0]; o0.y = acc[1]+bb[1]; o0.z = acc[2]+bb[2]; o0.w = acc[3]+bb[3];
  o1.x = acc[4]+bb[4]; o1.y = acc[5]+bb[5]; o1.z = acc[6]+bb[6]; o1.w = acc[7]+bb[7];
  *(float4*)&O[(size_t)r * 8 + 0] = o0;
  *(float4*)&O[(size_t)r * 8 + 4] = o1;
}

extern "C" void kernel_launch(void* const* d_in, const int* in_sizes, int n_in,
                              void* d_out, int out_size, void* d_ws, size_t ws_size,
                              hipStream_t stream) {
  const float* seq = (const float*)d_in[0];
  const int*   ei  = (const int*)d_in[1];
  const int*   esrc = ei;
  const int*   edst = ei + NE;
  const float* W1 = (const float*)d_in[2];
  const float* b1 = (const float*)d_in[3];
  const float* W2 = (const float*)d_in[4];
  const float* b2 = (const float*)d_in[5];
  const float* Wc = (const float*)d_in[6];
  const float* bc = (const float*)d_in[7];
  float* out = (float*)d_out;

  char* ws = (char*)d_ws;
  size_t o = 0;
  auto alloc = [&](size_t bytes) -> void* {
    void* p = ws + o;
    o += (bytes + 255) & ~(size_t)255;
    return p;
  };
  int*   deg  = (int*)alloc((size_t)NN * 4);
  float* dinv = (float*)alloc((size_t)NN * 4);
  int*   offs = (int*)alloc((size_t)(NN + 1) * 4);
  int*   bsum = (int*)alloc(64 * 4);
  int*   bh   = (int*)alloc((size_t)NBK * NSB * 4);
  int*   boff = (int*)alloc((size_t)NBK * NSB * 4);
  int*   btot = (int*)alloc((size_t)NBK * 4);
  int*   bbase= (int*)alloc((size_t)(NBK + 1) * 4);
  uint32_t* ebuf = (uint32_t*)alloc((size_t)NE * 4);
  unsigned short* csr = (unsigned short*)alloc((size_t)NE * 2);
  unsigned short* hbuf = (unsigned short*)alloc((size_t)NN * 128 * 2);
  float* rbuf = (float*)alloc((size_t)NN * 128 * 4);
  unsigned short* B1h = (unsigned short*)alloc((size_t)128 * 264 * 2);
  unsigned short* B1l = (unsigned short*)alloc((size_t)128 * 264 * 2);
  unsigned short* B2h = (unsigned short*)alloc((size_t)64 * 136 * 2);
  unsigned short* B2l = (unsigned short*)alloc((size_t)64 * 136 * 2);

  const int nb = (NN + 1023) / 1024;
  k_hist  <<<NSB, 256, 0, stream>>>(edst, bh);
  k_bscan <<<NBK, 512, 0, stream>>>(bh, boff, btot);
  k_btscan<<<1, 256, 0, stream>>>(btot, bbase);
  k_scatter<<<NSB, 256, 0, stream>>>(esrc, edst, bbase, boff, ebuf);
  k_bdeg  <<<NBK, 256, 0, stream>>>(ebuf, bbase, deg, dinv);
  k_scan1 <<<nb, 1024, 0, stream>>>(deg, offs, bsum);
  k_scan2 <<<1, 64, 0, stream>>>(bsum, offs, nb);
  k_scan3 <<<nb, 1024, 0, stream>>>(offs, bsum);
  k_fill2 <<<NBK, 256, 0, stream>>>(ebuf, bbase, offs, csr);

  k_bsplit<<<(256 * 128 + 255) / 256, 256, 0, stream>>>(W1, B1h, B1l, 256, 128, 264);
  k_bsplit<<<(128 * 64 + 255) / 256, 256, 0, stream>>>(W2, B2h, B2l, 128, 64, 136);

  const int gblocks = (NN + 63) / 64;
  k_gemm1<<<gblocks, 256, 0, stream>>>(seq, B1h, B1l, dinv, hbuf);
  k_agg1 <<<(NN * 64) / 256, 256, 0, stream>>>(hbuf, csr, offs, dinv, b1, rbuf);
  k_gemm2<<<gblocks, 256, 0, stream>>>(rbuf, B2h, B2l, dinv, hbuf);
  k_agg2 <<<(NN * 32) / 256, 256, 0, stream>>>(hbuf, csr, offs, dinv, b2, rbuf);
  k_gemm3<<<(NN + 255) / 256, 256, 0, stream>>>(rbuf, Wc, bc, out);
}